// Round 3
// baseline (825.550 us; speedup 1.0000x reference)
//
#include <hip/hip_runtime.h>
#include <math.h>

// Problem constants: B=16, T=4096, D=512, N=9, K=1024, d=8
#define ROWS   65536

// ---- workspace float offsets ----
#define WS_WPAD 0          // W_in_all padded [512][96]: col cc=8i+c at (cc/9)*12+cc%9
#define WS_WOUT 49152      // W_out_all [72][512], row jr = 8j+a
#define WS_CBN  86016      // normalized codebooks [9][1024][8] (row-major per code)
#define WS_SC   159744     // sum(cb_n^2) [9][1024]
#define WS_M    168960     // M[j][i][a*8+b] = sum_t Wout[j][a][t]*Win[i][t][b]
#define WS_CACC 174144     // [9][8]: sum_{j<i} out_b_j @ W_in_i
#define WS_SOB  174216     // [512]: sum_j out_b_j
#define WS_LOSS 174728     // double accumulator (8B aligned)

// ---- output float offsets ----
#define OUT_CODES 33554432
#define OUT_LAT   34144256
#define OUT_CLOSS 38862848
#define OUT_CBLOSS 38862849

__device__ __forceinline__ int pcol(int cc){ return (cc/9)*12 + (cc%9); }

// ---------------- prep1: weight-norm + codebook normalize ----------------
__global__ __launch_bounds__(256) void prep1(const float* __restrict__ in_v,
    const float* __restrict__ in_g, const float* __restrict__ out_v,
    const float* __restrict__ out_g, const float* __restrict__ out_b,
    const float* __restrict__ cb, float* __restrict__ ws)
{
    int t = blockIdx.x*256 + threadIdx.x;
    if (t < 9216) {
        // codebook normalize: (i,k), row-major [k][8] output
        int i = t >> 10, k = t & 1023;
        const float* p = cb + (i*1024 + k)*8;
        float v[8]; float ssq = 0.f;
        #pragma unroll
        for (int c=0;c<8;c++){ v[c]=p[c]; ssq = fmaf(v[c],v[c],ssq); }
        float den = fmaxf(sqrtf(ssq), 1e-12f);
        float sc = 0.f;
        float* dst = ws + WS_CBN + (i*1024+k)*8;
        #pragma unroll
        for (int c=0;c<8;c++){ float cn = v[c]/den; dst[c] = cn; sc = fmaf(cn,cn,sc); }
        ws[WS_SC + i*1024 + k] = sc;
    } else if (t < 13824) {
        // W_out: (j, t) norm over a-axis
        int r = t - 9216; int j = r >> 9, tt = r & 511;
        float v[8]; float ssq = 0.f;
        #pragma unroll
        for (int a=0;a<8;a++){ v[a]=out_v[(j*8+a)*512+tt]; ssq=fmaf(v[a],v[a],ssq); }
        float den = fmaxf(sqrtf(ssq), 1e-12f);
        float g = out_g[j*512+tt];
        #pragma unroll
        for (int a=0;a<8;a++) ws[WS_WOUT + (j*8+a)*512 + tt] = g*v[a]/den;
    } else if (t < 18432) {
        // W_in: one wave per (i,c) column, norm over 512 rows
        int r = t - 13824;
        int w = r >> 6, l = r & 63;
        int i = w >> 3, c = w & 7;
        float v[8]; float ssq = 0.f;
        #pragma unroll
        for (int u=0;u<8;u++){ v[u] = in_v[(i*512 + l*8+u)*8 + c]; ssq = fmaf(v[u],v[u],ssq); }
        #pragma unroll
        for (int off=1; off<64; off<<=1) ssq += __shfl_xor(ssq, off, 64);
        float den = fmaxf(sqrtf(ssq), 1e-12f);
        float g = in_g[i*8+c];
        int pc = pcol(i*8+c);
        #pragma unroll
        for (int u=0;u<8;u++) ws[WS_WPAD + (l*8+u)*96 + pc] = g*v[u]/den;
    } else if (t < 18944) {
        int tt = t - 18432;
        float s = 0.f;
        for (int j=0;j<9;j++) s += out_b[j*512+tt];
        ws[WS_SOB + tt] = s;
    } else if (t == 18944) {
        *(double*)&ws[WS_LOSS] = 0.0;
    }
}

// ---------------- prep2: cross-term tables M and Cacc (8 lanes per output) ----
__global__ __launch_bounds__(256) void prep2(const float* __restrict__ out_b,
                                             float* __restrict__ ws)
{
    int g = blockIdx.x*256 + threadIdx.x;
    if (g < 41472) {
        int oi = g >> 3, part = g & 7;
        int j = oi / 576; int rem = oi % 576; int i = rem >> 6; int ab = rem & 63;
        int a = ab >> 3, b = ab & 7;
        int pc = pcol(i*8+b);
        const float* wo = ws + WS_WOUT + (j*8+a)*512 + part*64;
        const float* wp = ws + WS_WPAD + (part*64)*96 + pc;
        float s = 0.f;
        #pragma unroll
        for (int u=0; u<16; u++) {
            float4 w4 = *(const float4*)(wo + u*4);
            s = fmaf(w4.x, wp[(u*4+0)*96], s);
            s = fmaf(w4.y, wp[(u*4+1)*96], s);
            s = fmaf(w4.z, wp[(u*4+2)*96], s);
            s = fmaf(w4.w, wp[(u*4+3)*96], s);
        }
        #pragma unroll
        for (int off=1; off<8; off<<=1) s += __shfl_xor(s, off, 64);
        if (part == 0) ws[WS_M + oi] = s;
    } else if (g < 42048) {
        int r = g - 41472;
        int oi = r >> 3, part = r & 7;
        int i = oi >> 3, b = oi & 7;
        int pc = pcol(i*8+b);
        float s = 0.f;
        for (int u=0; u<64; u++) {
            int tt = part*64 + u;
            float bb = 0.f;
            for (int j=0;j<i;j++) bb += out_b[j*512+tt];
            s = fmaf(bb, ws[WS_WPAD + tt*96+pc], s);
        }
        #pragma unroll
        for (int off=1; off<8; off<<=1) s += __shfl_xor(s, off, 64);
        if (part == 0) ws[WS_CACC + oi] = s;
    }
}

// ---------------- gemm_in: P = z @ W_in_all + in_b  -> latents region ----------------
// register double-buffer prefetch of the next k-tile
__global__ __launch_bounds__(256) void gemm_in(const float* __restrict__ z,
    const float* __restrict__ in_b, const float* __restrict__ ws, float* __restrict__ out)
{
    __shared__ float AsT[32*132];
    __shared__ float Bs[32*96];
    int tid = threadIdx.x;
    int rowbase = blockIdx.x * 128;
    int tr = tid & 31, tc = tid >> 5;
    float acc[4][9];
    #pragma unroll
    for (int r=0;r<4;r++){
        #pragma unroll
        for(int c=0;c<9;c++) acc[r][c]=0.f;
    }
    int kq = tid & 7, rr = tid >> 3;
    const float* zb = z + (size_t)rowbase*512;
    float4 az[4], bz[3];
    #pragma unroll
    for (int p=0;p<4;p++) az[p] = *(const float4*)(zb + (size_t)(rr+p*32)*512 + kq*4);
    #pragma unroll
    for (int p=0;p<3;p++) bz[p] = *(const float4*)(ws + WS_WPAD + (p*256+tid)*4);
    for (int kk=0; kk<16; kk++) {
        #pragma unroll
        for (int p=0;p<4;p++){
            int row = rr + p*32;
            AsT[(kq*4+0)*132 + row] = az[p].x;
            AsT[(kq*4+1)*132 + row] = az[p].y;
            AsT[(kq*4+2)*132 + row] = az[p].z;
            AsT[(kq*4+3)*132 + row] = az[p].w;
        }
        #pragma unroll
        for (int p=0;p<3;p++) *(float4*)(Bs + (p*256+tid)*4) = bz[p];
        __syncthreads();
        if (kk < 15){
            #pragma unroll
            for (int p=0;p<4;p++) az[p] = *(const float4*)(zb + (size_t)(rr+p*32)*512 + (kk+1)*32 + kq*4);
            #pragma unroll
            for (int p=0;p<3;p++) bz[p] = *(const float4*)(ws + WS_WPAD + (kk+1)*32*96 + (p*256+tid)*4);
        }
        #pragma unroll 4
        for (int k=0;k<32;k++){
            float4 a  = *(const float4*)(AsT + k*132 + tr*4);
            float4 b0 = *(const float4*)(Bs + k*96 + tc*12);
            float4 b1 = *(const float4*)(Bs + k*96 + tc*12 + 4);
            float  b8 = Bs[k*96 + tc*12 + 8];
            float av[4] = {a.x,a.y,a.z,a.w};
            float bv[9] = {b0.x,b0.y,b0.z,b0.w,b1.x,b1.y,b1.z,b1.w,b8};
            #pragma unroll
            for (int r=0;r<4;r++){
                #pragma unroll
                for (int c=0;c<9;c++) acc[r][c] = fmaf(av[r], bv[c], acc[r][c]);
            }
        }
        __syncthreads();
    }
    #pragma unroll
    for (int c=0;c<9;c++){
        int cc = tc*9+c;
        float bias = in_b[cc];
        #pragma unroll
        for (int r=0;r<4;r++){
            int row = rowbase + tr*4 + r;
            out[OUT_LAT + (size_t)row*72 + cc] = acc[r][c] + bias;
        }
    }
}

// ---------------- step v2: one quantizer stage (launched 9x) ----------------
// Wave owns 8 rows (zen replicated in regs); 64 lanes partition the 1024 codes.
// Lane L scans codes {it*64+L}; LDS reads are lane-unique contiguous b128.
__global__ __launch_bounds__(256) void step_kernel(int i,
    const float* __restrict__ cbooks, float* __restrict__ ws, float* __restrict__ out)
{
    __shared__ float CB0[1024*4];   // dims 0-3 per code
    __shared__ float CB1[1024*4];   // dims 4-7 per code
    __shared__ float SCs[1024];
    __shared__ float Ms[512];       // M[jj][a*8+b] for jj<i
    __shared__ float SCR[4*96];     // per-wave: 8 rows x 12 (zen[8], se)
    __shared__ float warr[4];
    int tid = threadIdx.x;

    // ---- stage codebook i into LDS (split halves, b128-friendly) ----
    const float* cbn = ws + WS_CBN + i*8192;
    #pragma unroll
    for (int u=0; u<4; u++){
        int c = u*256 + tid;
        float4 h0 = *(const float4*)(cbn + c*8);
        float4 h1 = *(const float4*)(cbn + c*8 + 4);
        *(float4*)(CB0 + c*4) = h0;
        *(float4*)(CB1 + c*4) = h1;
    }
    *(float4*)(SCs + tid*4) = *(const float4*)(ws + WS_SC + i*1024 + tid*4);
    if (tid < i*64)       Ms[tid]     = ws[WS_M + ((tid>>6)*9 + i)*64 + (tid&63)];
    if (tid + 256 < i*64) Ms[tid+256] = ws[WS_M + (((tid+256)>>6)*9 + i)*64 + (tid&63)];

    int wave = tid >> 6, L = tid & 63;
    int r = L & 7, jj = L >> 3;
    int row = blockIdx.x*32 + wave*8 + r;
    __syncthreads();

    // ---- corrections: lane (r,jj) computes q_jj . M[jj][i] partial ----
    float part[8] = {0,0,0,0,0,0,0,0};
    if (jj < i) {
        int kj = (int)out[OUT_CODES + (size_t)row*9 + jj];
        const float* qp = cbooks + ((size_t)(jj*1024+kj))*8;
        float4 q0 = *(const float4*)qp, q1 = *(const float4*)(qp+4);
        float qa[8] = {q0.x,q0.y,q0.z,q0.w,q1.x,q1.y,q1.z,q1.w};
        #pragma unroll
        for (int a=0;a<8;a++){
            float4 m0 = *(const float4*)(Ms + jj*64 + a*8);
            float4 m1 = *(const float4*)(Ms + jj*64 + a*8 + 4);
            part[0]=fmaf(qa[a],m0.x,part[0]); part[1]=fmaf(qa[a],m0.y,part[1]);
            part[2]=fmaf(qa[a],m0.z,part[2]); part[3]=fmaf(qa[a],m0.w,part[3]);
            part[4]=fmaf(qa[a],m1.x,part[4]); part[5]=fmaf(qa[a],m1.y,part[5]);
            part[6]=fmaf(qa[a],m1.z,part[6]); part[7]=fmaf(qa[a],m1.w,part[7]);
        }
    }
    #pragma unroll
    for (int off=8; off<64; off<<=1){
        #pragma unroll
        for (int b=0;b<8;b++) part[b] += __shfl_xor(part[b], off, 64);
    }

    // ---- lanes 0-7 finalize z_e for their row, normalize, share ----
    float ze[8];
    if (jj == 0) {
        float* lat = out + OUT_LAT + (size_t)row*72 + i*8;
        float4 p0 = *(const float4*)lat, p1 = *(const float4*)(lat+4);
        float P[8] = {p0.x,p0.y,p0.z,p0.w,p1.x,p1.y,p1.z,p1.w};
        #pragma unroll
        for (int b=0;b<8;b++) ze[b] = P[b] - ws[WS_CACC + i*8 + b] - part[b];
        float4 z0 = {ze[0],ze[1],ze[2],ze[3]};
        float4 z1 = {ze[4],ze[5],ze[6],ze[7]};
        *(float4*)lat = z0; *(float4*)(lat+4) = z1;   // latents = z_e
        float ssq = 0.f;
        #pragma unroll
        for (int c=0;c<8;c++) ssq = fmaf(ze[c],ze[c],ssq);
        float den = fmaxf(sqrtf(ssq), 1e-12f);
        float zen[8];
        #pragma unroll
        for (int c=0;c<8;c++) zen[c] = ze[c]/den;
        float se = 0.f;
        #pragma unroll
        for (int c=0;c<8;c++) se = fmaf(zen[c],zen[c],se);
        float* s = SCR + wave*96 + r*12;
        float4 w0 = {zen[0],zen[1],zen[2],zen[3]};
        float4 w1 = {zen[4],zen[5],zen[6],zen[7]};
        *(float4*)s = w0; *(float4*)(s+4) = w1; s[8] = se;
    }
    __syncthreads();

    // ---- load all 8 rows' zen/se into regs ----
    float zr[8][8], ser[8];
    #pragma unroll
    for (int rr=0; rr<8; rr++){
        const float* s = SCR + wave*96 + rr*12;
        float4 a = *(const float4*)s, b = *(const float4*)(s+4);
        zr[rr][0]=a.x; zr[rr][1]=a.y; zr[rr][2]=a.z; zr[rr][3]=a.w;
        zr[rr][4]=b.x; zr[rr][5]=b.y; zr[rr][6]=b.z; zr[rr][7]=b.w;
        ser[rr]=s[8];
    }

    // ---- scan: lane L handles codes it*64+L (ascending -> first-min in lane) ----
    float bd[8]; int bk[8];
    #pragma unroll
    for (int rr=0;rr<8;rr++){ bd[rr]=1e30f; bk[rr]=0; }
    #pragma unroll 2
    for (int it=0; it<16; it++){
        int c = it*64 + L;
        float4 v0 = *(const float4*)(CB0 + c*4);
        float4 v1 = *(const float4*)(CB1 + c*4);
        float scv = SCs[c];
        #pragma unroll
        for (int rr=0; rr<8; rr++){
            float d = 0.f;
            d = fmaf(zr[rr][0], v0.x, d); d = fmaf(zr[rr][1], v0.y, d);
            d = fmaf(zr[rr][2], v0.z, d); d = fmaf(zr[rr][3], v0.w, d);
            d = fmaf(zr[rr][4], v1.x, d); d = fmaf(zr[rr][5], v1.y, d);
            d = fmaf(zr[rr][6], v1.z, d); d = fmaf(zr[rr][7], v1.w, d);
            float t = fmaf(d, -2.0f, ser[rr]) + scv;
            bool cg = t < bd[rr];
            bk[rr] = cg ? c : bk[rr];
            bd[rr] = cg ? t : bd[rr];
        }
    }
    // ---- cross-lane argmin merge (tie -> smaller code) ----
    #pragma unroll
    for (int off=1; off<64; off<<=1){
        #pragma unroll
        for (int rr=0; rr<8; rr++){
            float od = __shfl_xor(bd[rr], off, 64);
            int   ok = __shfl_xor(bk[rr], off, 64);
            if (od < bd[rr] || (od == bd[rr] && ok < bk[rr])) { bd[rr]=od; bk[rr]=ok; }
        }
    }

    // ---- epilogue: lane r<8 writes code + loss for its row ----
    float lpart = 0.f;
    if (L < 8) {
        int k = bk[L];
        out[OUT_CODES + (size_t)row*9 + i] = (float)k;
        const float* qp = cbooks + ((size_t)(i*1024+k))*8;
        #pragma unroll
        for (int c=0;c<8;c++){ float dd = ze[c]-qp[c]; lpart = fmaf(dd,dd,lpart); }
    }
    #pragma unroll
    for (int off=1; off<64; off<<=1) lpart += __shfl_xor(lpart, off, 64);
    if (L == 0) warr[wave] = lpart;
    __syncthreads();
    if (tid == 0){
        double bs = (double)warr[0]+(double)warr[1]+(double)warr[2]+(double)warr[3];
        atomicAdd((double*)&ws[WS_LOSS], bs);
    }
}

// ---------------- gemm_out: z_q = Q @ W_out_all + sum_out_b ----------------
__global__ __launch_bounds__(256) void gemm_out(const float* __restrict__ cbooks,
    const float* __restrict__ ws, float* __restrict__ out)
{
    __shared__ float QL[64*76];
    __shared__ float Ws[72*128];
    int tid = threadIdx.x;
    int rowbase = blockIdx.x*64;
    if (tid < 64){
        int row = rowbase + tid;
        for (int j=0;j<9;j++){
            int kj = (int)out[OUT_CODES + (size_t)row*9 + j];
            const float* qp = cbooks + (j*1024+kj)*8;
            float4 q0 = *(const float4*)qp;
            float4 q1 = *(const float4*)(qp+4);
            *(float4*)(QL + tid*76 + j*8)     = q0;
            *(float4*)(QL + tid*76 + j*8 + 4) = q1;
        }
    }
    int tr = tid & 15, tc = tid >> 4;
    for (int cc=0; cc<4; cc++){
        __syncthreads();
        #pragma unroll
        for (int p=0;p<9;p++){
            int idx = p*256 + tid;
            int jr = idx >> 5; int cq = idx & 31;
            *(float4*)(Ws + jr*128 + cq*4) = *(const float4*)(ws + WS_WOUT + jr*512 + cc*128 + cq*4);
        }
        __syncthreads();
        float acc[4][8];
        #pragma unroll
        for (int r=0;r<4;r++){
            #pragma unroll
            for (int c=0;c<8;c++) acc[r][c]=0.f;
        }
        #pragma unroll 4
        for (int k=0;k<72;k++){
            float a0 = QL[(tr*4+0)*76 + k];
            float a1 = QL[(tr*4+1)*76 + k];
            float a2 = QL[(tr*4+2)*76 + k];
            float a3 = QL[(tr*4+3)*76 + k];
            float4 b0 = *(const float4*)(Ws + k*128 + tc*8);
            float4 b1 = *(const float4*)(Ws + k*128 + tc*8 + 4);
            float bv[8] = {b0.x,b0.y,b0.z,b0.w,b1.x,b1.y,b1.z,b1.w};
            float av[4] = {a0,a1,a2,a3};
            #pragma unroll
            for (int r=0;r<4;r++){
                #pragma unroll
                for (int c=0;c<8;c++) acc[r][c] = fmaf(av[r], bv[c], acc[r][c]);
            }
        }
        float4 s0 = *(const float4*)(ws + WS_SOB + cc*128 + tc*8);
        float4 s1 = *(const float4*)(ws + WS_SOB + cc*128 + tc*8 + 4);
        #pragma unroll
        for (int r=0;r<4;r++){
            int row = rowbase + tr*4 + r;
            float4 o0 = {acc[r][0]+s0.x, acc[r][1]+s0.y, acc[r][2]+s0.z, acc[r][3]+s0.w};
            float4 o1 = {acc[r][4]+s1.x, acc[r][5]+s1.y, acc[r][6]+s1.z, acc[r][7]+s1.w};
            *(float4*)(out + (size_t)row*512 + cc*128 + tc*8)     = o0;
            *(float4*)(out + (size_t)row*512 + cc*128 + tc*8 + 4) = o1;
        }
    }
    if (blockIdx.x==0 && tid==0){
        double L = *(const double*)(ws + WS_LOSS);
        float lv = (float)(L * (1.0/524288.0));   // / (B*T*d)
        out[OUT_CLOSS]  = lv;
        out[OUT_CBLOSS] = lv;
    }
}

extern "C" void kernel_launch(void* const* d_in, const int* in_sizes, int n_in,
                              void* d_out, int out_size, void* d_ws, size_t ws_size,
                              hipStream_t stream) {
    const float* z     = (const float*)d_in[0];
    const float* in_v  = (const float*)d_in[1];
    const float* in_g  = (const float*)d_in[2];
    const float* in_b  = (const float*)d_in[3];
    const float* out_v = (const float*)d_in[4];
    const float* out_g = (const float*)d_in[5];
    const float* out_b = (const float*)d_in[6];
    const float* cb    = (const float*)d_in[7];
    float* out = (float*)d_out;
    float* ws  = (float*)d_ws;

    prep1<<<75, 256, 0, stream>>>(in_v, in_g, out_v, out_g, out_b, cb, ws);
    prep2<<<165, 256, 0, stream>>>(out_b, ws);
    gemm_in<<<512, 256, 0, stream>>>(z, in_b, ws, out);
    for (int i=0; i<9; i++)
        step_kernel<<<2048, 256, 0, stream>>>(i, cb, ws, out);
    gemm_out<<<1024, 256, 0, stream>>>(cb, ws, out);
}